// Round 4
// baseline (554.709 us; speedup 1.0000x reference)
//
#include <hip/hip_runtime.h>

#define NN 50000
#define NE 800000
#define INC 32
#define HH 64
#define H2 128
#define OC 16
#define ON 17
#define NL 4
#define MEPS 1e-7f
#define LNE 1e-5f
#define SCAN_BLOCKS 196   /* ceil(50000/256) */

// ---------- ordered-uint encoding for float atomic max ----------
__device__ __forceinline__ unsigned fenc(float x) {
    unsigned u = __float_as_uint(x);
    return (u & 0x80000000u) ? ~u : (u | 0x80000000u);
}
__device__ __forceinline__ float fdec(unsigned u) {
    return (u & 0x80000000u) ? __uint_as_float(u & 0x7fffffffu)
                             : __uint_as_float(~u);
}
// ---------- bf16 helpers (RNE) ----------
__device__ __forceinline__ unsigned short f2b(float x) {
    unsigned b = __float_as_uint(x);
    b += 0x7FFFu + ((b >> 16) & 1u);
    return (unsigned short)(b >> 16);
}
__device__ __forceinline__ float b2f(unsigned short u) {
    return __uint_as_float(((unsigned)u) << 16);
}

// ---------- CSR build ----------
__global__ __launch_bounds__(256) void k_hist2(const int* __restrict__ dst, int* __restrict__ counts,
                                               int* __restrict__ rank) {
    int e = blockIdx.x * 256 + threadIdx.x;
    if (e < NE) rank[e] = atomicAdd(&counts[dst[e]], 1);
}

__global__ __launch_bounds__(256) void k_scan1(const int* __restrict__ counts,
                                               int* __restrict__ incl, int* __restrict__ bsums) {
    __shared__ int s[256];
    int t = threadIdx.x;
    int i = blockIdx.x * 256 + t;
    int v = (i < NN) ? counts[i] : 0;
    s[t] = v;
    __syncthreads();
    for (int off = 1; off < 256; off <<= 1) {
        int x = (t >= off) ? s[t - off] : 0;
        __syncthreads();
        s[t] += x;
        __syncthreads();
    }
    if (i < NN) incl[i] = s[t];
    if (t == 255) bsums[blockIdx.x] = s[255];
}

__global__ __launch_bounds__(256) void k_scan2(int* __restrict__ bsums) {
    __shared__ int s[256];
    int t = threadIdx.x;
    int v = (t < SCAN_BLOCKS) ? bsums[t] : 0;
    s[t] = v;
    __syncthreads();
    for (int off = 1; off < 256; off <<= 1) {
        int x = (t >= off) ? s[t - off] : 0;
        __syncthreads();
        s[t] += x;
        __syncthreads();
    }
    if (t < SCAN_BLOCKS) bsums[t] = s[t] - v;  // exclusive
}

__global__ __launch_bounds__(256) void k_scan3(const int* __restrict__ counts,
                                               int* __restrict__ rowst, const int* __restrict__ bsums) {
    int i = blockIdx.x * 256 + threadIdx.x;
    if (i < NN) rowst[i] = rowst[i] - counts[i] + bsums[blockIdx.x];
}

__global__ __launch_bounds__(256) void k_scatter2(const int* __restrict__ src, const int* __restrict__ dst,
                                                  const int* __restrict__ rank, const int* __restrict__ rowst,
                                                  int* __restrict__ ssrc) {
    int e = blockIdx.x * 256 + threadIdx.x;
    if (e < NE) ssrc[rowst[dst[e]] + rank[e]] = src[e];
}

// ---------- node encoder: h = x @ W + b  ([N,32]@[32,64]), also bf16 shadow ----------
__global__ __launch_bounds__(256) void k_encoder(const float* __restrict__ x, const float* __restrict__ W,
                                                 const float* __restrict__ b, float* __restrict__ h,
                                                 unsigned short* __restrict__ hbf) {
    __shared__ float Ws[INC * HH];
    __shared__ float bs[HH];
    int tid = threadIdx.x;
    for (int i = tid; i < INC * HH; i += 256) Ws[i] = W[i];
    if (tid < HH) bs[tid] = b[tid];
    __syncthreads();
    int wid = tid >> 6, lane = tid & 63;
    int n = blockIdx.x * 4 + wid;
    if (n >= NN) return;
    float v = (lane < INC) ? x[(size_t)n * INC + lane] : 0.f;
    float acc = bs[lane];
    #pragma unroll
    for (int k = 0; k < INC; ++k)
        acc += __shfl(v, k) * Ws[k * HH + lane];
    h[(size_t)n * HH + lane] = acc;
    hbf[(size_t)n * HH + lane] = f2b(acc);
}

// ---------- per-dst softmax aggregation, dual-row gathers ----------
__global__ __launch_bounds__(256) void k_agg(const float* __restrict__ y,
                                             const unsigned short* __restrict__ ybf,
                                             const int* __restrict__ rowst,
                                             const int* __restrict__ counts, const int* __restrict__ ssrc,
                                             const float* __restrict__ tp, float* __restrict__ ag) {
    int tid = threadIdx.x;
    int wid = tid >> 6, lane = tid & 63;
    int n = blockIdx.x * 4 + wid;
    if (n >= NN) return;
    float tval = *tp;
    int start = rowst[n];
    int deg = counts[n];
    float Sa = 0.f, Sma = 0.f;
    if (deg > 0 && deg <= 64) {
        int myidx = (lane < deg) ? ssrc[start + lane] : 0;
        int half = lane >> 5;      // edge parity this lane handles
        int col = lane & 31;       // channel-pair index
        float Sa0 = 0.f, Sa1 = 0.f, Sm0 = 0.f, Sm1 = 0.f;
        for (int base = 0; base < deg; base += 16) {
            float c0[8], c1[8];
            int eidx[8];
            #pragma unroll
            for (int i = 0; i < 8; ++i) {
                int e = base + 2 * i + half;
                eidx[i] = e;
                int es = (e < deg) ? e : (deg - 1);
                int s = __shfl(myidx, es);
                unsigned v = *(const unsigned*)(ybf + (size_t)s * HH + col * 2);
                c0[i] = b2f((unsigned short)(v & 0xffffu));
                c1[i] = b2f((unsigned short)(v >> 16));
            }
            #pragma unroll
            for (int i = 0; i < 8; ++i) {
                bool ok = eidx[i] < deg;
                float m0 = fmaxf(c0[i], 0.f) + MEPS;
                float m1 = fmaxf(c1[i], 0.f) + MEPS;
                float a0 = ok ? __expf(tval * m0) : 0.f;
                float a1 = ok ? __expf(tval * m1) : 0.f;
                Sa0 += a0; Sm0 += m0 * a0;
                Sa1 += a1; Sm1 += m1 * a1;
            }
        }
        Sa0 += __shfl_xor(Sa0, 32); Sa1 += __shfl_xor(Sa1, 32);
        Sm0 += __shfl_xor(Sm0, 32); Sm1 += __shfl_xor(Sm1, 32);
        int srcl = lane >> 1;
        float saA = __shfl(Sa0, srcl), saB = __shfl(Sa1, srcl);
        float smA = __shfl(Sm0, srcl), smB = __shfl(Sm1, srcl);
        Sa = (lane & 1) ? saB : saA;
        Sma = (lane & 1) ? smB : smA;
    } else if (deg > 64) {
        for (int e = 0; e < deg; ++e) {
            int s = ssrc[start + e];
            float v = b2f(ybf[(size_t)s * HH + lane]);
            float m = fmaxf(v, 0.f) + MEPS;
            float a = __expf(tval * m);
            Sa += a; Sma += m * a;
        }
    }
    float agg = Sma / fmaxf(Sa, MEPS);  // deg==0 -> 0
    ag[(size_t)n * HH + lane] = agg + y[(size_t)n * HH + lane];
}

// ---------- fused MLP: U = ag@W1+b1 ; U = relu(LN128(U)) ; o = U@W2+b2 (+hres) -> hout
//            optional epilogue: y = relu(LN64(o)) + bf16 shadow (next layer's input)
// U tile stored bf16 + LN-stats aliased into dead tile space: LDS 72.7 -> 52.3 KB
// -> 3 blocks/CU (LDS-issue-bound kernel, measured round 3: 59.6us, 68% LDS-pipe util).
// NOTE: GEMM inner loops MUST stay k+=2/float2 form; k+=4/float4 spills (round 2: VGPR=256,
// 380MB scratch/dispatch, 287us).
__global__ __launch_bounds__(256) void k_mlp(
    const float* __restrict__ ag,
    const float* __restrict__ W1, const float* __restrict__ b1,
    const float* __restrict__ mlg, const float* __restrict__ mlb,
    const float* __restrict__ W2, const float* __restrict__ b2,
    const float* __restrict__ hres, float* __restrict__ hout,
    const float* __restrict__ lng1, const float* __restrict__ lnb1,
    float* __restrict__ y, unsigned short* __restrict__ ybf)
{
    __shared__ float As[64 * 68];        // input tile; doubles as LN128-stats + epilogue scratch
    __shared__ float UsRaw[64 * 136 / 2];// bf16 U tile (stride 136 shorts); doubles as epilogue stats
    __shared__ float Wb[64 * 64];        // 16KB weight chunk
    __shared__ float bbA[H2], mg[H2], mbv[H2], bbB[HH], lgN[HH], lbN[HH];
    unsigned short* UsB = (unsigned short*)UsRaw;
    // LN128 stats live in As (dead between gemmA pass1 and epilogue):
    float* ps1 = As;       float* psq1 = As + 256;
    float* mus1 = As + 512; float* rss1 = As + 576;
    // epilogue stats live in UsRaw (dead after gemmB):
    float* ps2 = UsRaw;       float* psq2 = UsRaw + 256;
    float* mus2 = UsRaw + 512; float* rss2 = UsRaw + 576;
    int tid = threadIdx.x;
    int nb = blockIdx.x * 64;
    int tx = tid & 15, ty = tid >> 4;
    int r0 = ty * 4, c0 = tx * 4;

    // ---- stage input tile, W1 half 0, and small vectors
    {
        int row = tid >> 2, cb = (tid & 3) * 16;
        int n = nb + row;
        float4* dp = (float4*)(As + row * 68 + cb);
        if (n < NN) {
            const float4* sp = (const float4*)(ag + (size_t)n * HH + cb);
            #pragma unroll
            for (int i = 0; i < 4; ++i) dp[i] = sp[i];
        } else {
            float4 z = {0.f, 0.f, 0.f, 0.f};
            #pragma unroll
            for (int i = 0; i < 4; ++i) dp[i] = z;
        }
    }
    for (int i = tid; i < 1024; i += 256) {
        int k = i >> 4, cq = i & 15;
        ((float4*)Wb)[i] = ((const float4*)W1)[k * 32 + cq];           // cols 0..63
    }
    if (tid < H2) { bbA[tid] = b1[tid]; mg[tid] = mlg[tid]; mbv[tid] = mlb[tid]; }
    else if (tid < H2 + HH) {
        int j = tid - H2;
        bbB[j] = b2[j];
        if (lng1) { lgN[j] = lng1[j]; lbN[j] = lnb1[j]; }
    }
    __syncthreads();

    // ---- gemmA pass 0 (output cols 0..63)
    {
        float acc[4][4] = {};
        #pragma unroll 8
        for (int k = 0; k < HH; k += 2) {
            float4 w0 = ((const float4*)Wb)[k * 16 + tx];
            float4 w1 = ((const float4*)Wb)[(k + 1) * 16 + tx];
            #pragma unroll
            for (int r = 0; r < 4; ++r) {
                float2 a2 = *(const float2*)(As + (r0 + r) * 68 + k);
                acc[r][0] += a2.x * w0.x + a2.y * w1.x;
                acc[r][1] += a2.x * w0.y + a2.y * w1.y;
                acc[r][2] += a2.x * w0.z + a2.y * w1.z;
                acc[r][3] += a2.x * w0.w + a2.y * w1.w;
            }
        }
        #pragma unroll
        for (int r = 0; r < 4; ++r) {
            ushort4 st;
            st.x = f2b(acc[r][0] + bbA[c0]);     st.y = f2b(acc[r][1] + bbA[c0 + 1]);
            st.z = f2b(acc[r][2] + bbA[c0 + 2]); st.w = f2b(acc[r][3] + bbA[c0 + 3]);
            *(ushort4*)(UsB + (r0 + r) * 136 + c0) = st;
        }
    }
    __syncthreads();
    for (int i = tid; i < 1024; i += 256) {
        int k = i >> 4, cq = i & 15;
        ((float4*)Wb)[i] = ((const float4*)W1)[k * 32 + 16 + cq];      // cols 64..127
    }
    __syncthreads();

    // ---- gemmA pass 1 (output cols 64..127)
    {
        float acc[4][4] = {};
        #pragma unroll 8
        for (int k = 0; k < HH; k += 2) {
            float4 w0 = ((const float4*)Wb)[k * 16 + tx];
            float4 w1 = ((const float4*)Wb)[(k + 1) * 16 + tx];
            #pragma unroll
            for (int r = 0; r < 4; ++r) {
                float2 a2 = *(const float2*)(As + (r0 + r) * 68 + k);
                acc[r][0] += a2.x * w0.x + a2.y * w1.x;
                acc[r][1] += a2.x * w0.y + a2.y * w1.y;
                acc[r][2] += a2.x * w0.z + a2.y * w1.z;
                acc[r][3] += a2.x * w0.w + a2.y * w1.w;
            }
        }
        #pragma unroll
        for (int r = 0; r < 4; ++r) {
            ushort4 st;
            st.x = f2b(acc[r][0] + bbA[64 + c0]);     st.y = f2b(acc[r][1] + bbA[64 + c0 + 1]);
            st.z = f2b(acc[r][2] + bbA[64 + c0 + 2]); st.w = f2b(acc[r][3] + bbA[64 + c0 + 3]);
            *(ushort4*)(UsB + (r0 + r) * 136 + 64 + c0) = st;
        }
    }
    __syncthreads();   // As dead from here until epilogue; stats may live there

    // ---- LN(128) partials (bf16 pairs); stage W2 rows 0..63 in the shadow
    {
        int row = tid >> 2, q = tid & 3;
        const unsigned short* rp = UsB + row * 136;
        float s = 0.f, sq = 0.f;
        #pragma unroll
        for (int i = 0; i < 16; ++i) {
            unsigned v = *(const unsigned*)(rp + 8 * i + 2 * q);
            float a = b2f((unsigned short)(v & 0xffffu));
            float b = b2f((unsigned short)(v >> 16));
            s += a + b; sq += a * a + b * b;
        }
        ps1[tid] = s; psq1[tid] = sq;
    }
    for (int i = tid; i < 1024; i += 256)
        ((float4*)Wb)[i] = ((const float4*)W2)[i];                     // k-rows 0..63
    __syncthreads();
    if (tid < 64) {
        float s = ps1[tid * 4] + ps1[tid * 4 + 1] + ps1[tid * 4 + 2] + ps1[tid * 4 + 3];
        float sq = psq1[tid * 4] + psq1[tid * 4 + 1] + psq1[tid * 4 + 2] + psq1[tid * 4 + 3];
        float mu = s * (1.f / 128.f);
        float var = sq * (1.f / 128.f) - mu * mu;
        mus1[tid] = mu;
        rss1[tid] = rsqrtf(fmaxf(var, 0.f) + LNE);
    }
    __syncthreads();
    {
        int row = tid >> 2, q = tid & 3;
        float mu = mus1[row], rs = rss1[row];
        unsigned short* rp = UsB + row * 136;
        #pragma unroll
        for (int i = 0; i < 16; ++i) {
            unsigned* p = (unsigned*)(rp + 8 * i + 2 * q);
            unsigned v = *p;
            int c = 8 * i + 2 * q;
            float a = fmaxf((b2f((unsigned short)(v & 0xffffu)) - mu) * rs * mg[c] + mbv[c], 0.f);
            float b = fmaxf((b2f((unsigned short)(v >> 16)) - mu) * rs * mg[c + 1] + mbv[c + 1], 0.f);
            *p = ((unsigned)f2b(a)) | (((unsigned)f2b(b)) << 16);
        }
    }
    __syncthreads();

    // ---- gemmB (k 0..63, then k 64..127), bf16 A-operand
    float acc2[4][4] = {};
    #pragma unroll 8
    for (int k = 0; k < 64; k += 2) {
        float4 w0 = ((const float4*)Wb)[k * 16 + tx];
        float4 w1 = ((const float4*)Wb)[(k + 1) * 16 + tx];
        #pragma unroll
        for (int r = 0; r < 4; ++r) {
            unsigned ua = *(const unsigned*)(UsB + (r0 + r) * 136 + k);
            float ax = b2f((unsigned short)(ua & 0xffffu));
            float ay = b2f((unsigned short)(ua >> 16));
            acc2[r][0] += ax * w0.x + ay * w1.x;
            acc2[r][1] += ax * w0.y + ay * w1.y;
            acc2[r][2] += ax * w0.z + ay * w1.z;
            acc2[r][3] += ax * w0.w + ay * w1.w;
        }
    }
    __syncthreads();
    for (int i = tid; i < 1024; i += 256)
        ((float4*)Wb)[i] = ((const float4*)W2)[1024 + i];              // k-rows 64..127
    __syncthreads();
    #pragma unroll 8
    for (int k = 0; k < 64; k += 2) {
        float4 w0 = ((const float4*)Wb)[k * 16 + tx];
        float4 w1 = ((const float4*)Wb)[(k + 1) * 16 + tx];
        #pragma unroll
        for (int r = 0; r < 4; ++r) {
            unsigned ua = *(const unsigned*)(UsB + (r0 + r) * 136 + 64 + k);
            float ax = b2f((unsigned short)(ua & 0xffffu));
            float ay = b2f((unsigned short)(ua >> 16));
            acc2[r][0] += ax * w0.x + ay * w1.x;
            acc2[r][1] += ax * w0.y + ay * w1.y;
            acc2[r][2] += ax * w0.z + ay * w1.z;
            acc2[r][3] += ax * w0.w + ay * w1.w;
        }
    }

    // ---- epilogue: bias + residual, write h
    float4 o[4];
    #pragma unroll
    for (int r = 0; r < 4; ++r) {
        int n = nb + r0 + r;
        o[r].x = acc2[r][0] + bbB[c0];     o[r].y = acc2[r][1] + bbB[c0 + 1];
        o[r].z = acc2[r][2] + bbB[c0 + 2]; o[r].w = acc2[r][3] + bbB[c0 + 3];
        if (n < NN) {
            if (hres) {
                float4 hr = *(const float4*)(hres + (size_t)n * HH + c0);
                o[r].x += hr.x; o[r].y += hr.y; o[r].z += hr.z; o[r].w += hr.w;
            }
            *(float4*)(hout + (size_t)n * HH + c0) = o[r];
        }
    }
    if (!lng1) return;   // last layer: outg does the final LN itself (uniform exit)

    // ---- next-layer LN(64)+ReLU: row stats via LDS (As scratch, stats in UsRaw)
    #pragma unroll
    for (int r = 0; r < 4; ++r)
        *(float4*)(As + (r0 + r) * 68 + c0) = o[r];
    __syncthreads();   // also guarantees all waves finished gemmB UsB reads
    {
        int row = tid >> 2, q = tid & 3;
        const float* rp = As + row * 68;
        float s = 0.f, sq = 0.f;
        #pragma unroll
        for (int i = 0; i < 16; ++i) { float v = rp[q + 4 * i]; s += v; sq += v * v; }
        ps2[tid] = s; psq2[tid] = sq;
    }
    __syncthreads();
    if (tid < 64) {
        float s = ps2[tid * 4] + ps2[tid * 4 + 1] + ps2[tid * 4 + 2] + ps2[tid * 4 + 3];
        float sq = psq2[tid * 4] + psq2[tid * 4 + 1] + psq2[tid * 4 + 2] + psq2[tid * 4 + 3];
        float mu = s * (1.f / 64.f);
        float var = sq * (1.f / 64.f) - mu * mu;
        mus2[tid] = mu;
        rss2[tid] = rsqrtf(fmaxf(var, 0.f) + LNE);
    }
    __syncthreads();
    #pragma unroll
    for (int r = 0; r < 4; ++r) {
        int row = r0 + r;
        int n = nb + row;
        if (n >= NN) continue;
        float mu = mus2[row], rs = rss2[row];
        float4 v;
        v.x = fmaxf((o[r].x - mu) * rs * lgN[c0]     + lbN[c0],     0.f);
        v.y = fmaxf((o[r].y - mu) * rs * lgN[c0 + 1] + lbN[c0 + 1], 0.f);
        v.z = fmaxf((o[r].z - mu) * rs * lgN[c0 + 2] + lbN[c0 + 2], 0.f);
        v.w = fmaxf((o[r].w - mu) * rs * lgN[c0 + 3] + lbN[c0 + 3], 0.f);
        *(float4*)(y + (size_t)n * HH + c0) = v;
        ushort4 p;
        p.x = f2b(v.x); p.y = f2b(v.y); p.z = f2b(v.z); p.w = f2b(v.w);
        *(ushort4*)(ybf + (size_t)n * HH + c0) = p;
    }
}

// ---------- fused final LN + both heads (no fence; k_gdec decodes) ----------
// Weight tile transposed to [j][k] (pad 68): GEMM reads b128 over 4 k's.
__global__ __launch_bounds__(256) void k_outg(const float* __restrict__ h,
                                              const float* __restrict__ lng, const float* __restrict__ lnb,
                                              const float* __restrict__ gW, const float* __restrict__ gb,
                                              const float* __restrict__ nW, const float* __restrict__ nbp,
                                              float* __restrict__ dout, unsigned* __restrict__ genc) {
    __shared__ float As[64 * 68];     // h tile, then normalized in place
    __shared__ float WcT[33 * 68];    // [j][k]: j<17 n-head, j in [17,33) g-head
    __shared__ float Os[64 * 40];     // output tile
    __shared__ float bs[40];
    __shared__ float lg[HH], lb[HH];
    __shared__ float ps[256], psq[256];
    __shared__ float mus[64], rss[64];
    int tid = threadIdx.x;
    int nb = blockIdx.x * 64;
    for (int i = tid; i < HH * ON; i += 256) { int k = i / ON, j = i - k * ON; WcT[j * 68 + k] = nW[i]; }
    for (int i = tid; i < HH * OC; i += 256) { int k = i / OC, j = i - k * OC; WcT[(ON + j) * 68 + k] = gW[i]; }
    if (tid < ON) bs[tid] = nbp[tid];
    else if (tid < 33) bs[tid] = gb[tid - ON];
    if (tid < HH) { lg[tid] = lng[tid]; lb[tid] = lnb[tid]; }
    {
        int row = tid >> 2, cb = (tid & 3) * 16;
        int n = nb + row;
        float4* dp = (float4*)(As + row * 68 + cb);
        if (n < NN) {
            const float4* sp = (const float4*)(h + (size_t)n * HH + cb);
            #pragma unroll
            for (int i = 0; i < 4; ++i) dp[i] = sp[i];
        } else {
            float4 z = {0.f, 0.f, 0.f, 0.f};
            #pragma unroll
            for (int i = 0; i < 4; ++i) dp[i] = z;
        }
    }
    __syncthreads();
    {
        int row = tid >> 2, q = tid & 3;
        const float* rp = As + row * 68;
        float s = 0.f, sq = 0.f;
        #pragma unroll
        for (int i = 0; i < 16; ++i) { float v = rp[q + 4 * i]; s += v; sq += v * v; }
        ps[tid] = s; psq[tid] = sq;
    }
    __syncthreads();
    if (tid < 64) {
        float s = ps[tid * 4] + ps[tid * 4 + 1] + ps[tid * 4 + 2] + ps[tid * 4 + 3];
        float sq = psq[tid * 4] + psq[tid * 4 + 1] + psq[tid * 4 + 2] + psq[tid * 4 + 3];
        float mu = s * (1.f / 64.f);
        float var = sq * (1.f / 64.f) - mu * mu;
        mus[tid] = mu;
        rss[tid] = rsqrtf(fmaxf(var, 0.f) + LNE);
    }
    __syncthreads();
    {
        int row = tid >> 2, q = tid & 3;
        float mu = mus[row], rs = rss[row];
        float* rp = As + row * 68;
        #pragma unroll
        for (int i = 0; i < 16; ++i) {
            int c = q + 4 * i;
            rp[c] = fmaxf((rp[c] - mu) * rs * lg[c] + lb[c], 0.f);
        }
    }
    __syncthreads();
    int tx = tid & 15, ty = tid >> 4;
    int r0 = ty * 4;
    float acc[4][3];
    #pragma unroll
    for (int r = 0; r < 4; ++r) {
        acc[r][0] = bs[tx]; acc[r][1] = bs[tx + 16]; acc[r][2] = bs[32];
    }
    #pragma unroll
    for (int k = 0; k < HH; k += 4) {
        float4 w0 = *(const float4*)(WcT + tx * 68 + k);
        float4 w1 = *(const float4*)(WcT + (16 + tx) * 68 + k);
        float4 w2 = *(const float4*)(WcT + 32 * 68 + k);
        #pragma unroll
        for (int r = 0; r < 4; ++r) {
            float4 a = *(const float4*)(As + (r0 + r) * 68 + k);
            acc[r][0] += a.x * w0.x + a.y * w0.y + a.z * w0.z + a.w * w0.w;
            acc[r][1] += a.x * w1.x + a.y * w1.y + a.z * w1.z + a.w * w1.w;
            acc[r][2] += a.x * w2.x + a.y * w2.y + a.z * w2.z + a.w * w2.w;
        }
    }
    #pragma unroll
    for (int r = 0; r < 4; ++r) {
        Os[(r0 + r) * 40 + tx] = acc[r][0];
        Os[(r0 + r) * 40 + 16 + tx] = acc[r][1];
        if (tx == 0) Os[(r0 + r) * 40 + 32] = acc[r][2];
    }
    __syncthreads();
    // n-head store: linear index is exactly row-major [n][17] -> coalesced
    for (int i = tid; i < 64 * ON; i += 256) {
        int r = i / ON, j = i - r * ON;
        int n = nb + r;
        if (n < NN) dout[OC + (size_t)n * ON + j] = Os[r * 40 + j];
    }
    // g-head block max
    if (tid < OC) {
        int rmax = NN - nb; if (rmax > 64) rmax = 64;
        float m = -INFINITY;
        for (int r = 0; r < rmax; ++r) m = fmaxf(m, Os[r * 40 + ON + tid]);
        atomicMax(&genc[tid], fenc(m));
    }
}

__global__ void k_gdec(const unsigned* __restrict__ genc, float* __restrict__ dout) {
    int t = threadIdx.x;
    if (t < OC) dout[t] = fdec(genc[t]);
}

// ---------- launch ----------
extern "C" void kernel_launch(void* const* d_in, const int* in_sizes, int n_in,
                              void* d_out, int out_size, void* d_ws, size_t ws_size,
                              hipStream_t stream) {
    const float* x     = (const float*)d_in[0];
    const float* nodeW = (const float*)d_in[1];
    const float* nodeB = (const float*)d_in[2];
    const float* W1    = (const float*)d_in[3];
    const float* b1    = (const float*)d_in[4];
    const float* mlg   = (const float*)d_in[5];
    const float* mlb   = (const float*)d_in[6];
    const float* W2    = (const float*)d_in[7];
    const float* b2    = (const float*)d_in[8];
    const float* tt    = (const float*)d_in[9];
    const float* lng   = (const float*)d_in[10];
    const float* lnb   = (const float*)d_in[11];
    const int*   ei    = (const int*)d_in[12];
    const float* gW    = (const float*)d_in[13];
    const float* gb    = (const float*)d_in[14];
    const float* nW    = (const float*)d_in[15];
    const float* nbp   = (const float*)d_in[16];
    float* out = (float*)d_out;

    char* ws = (char*)d_ws;
    size_t off = 0;
    auto alloc = [&](size_t bytes) -> void* {
        void* p = ws + off;
        off = (off + bytes + 255) & ~(size_t)255;
        return p;
    };
    int* counts    = (int*)alloc((size_t)NN * 4);
    unsigned* genc = (unsigned*)alloc(64);
    size_t zero_end = off;
    int* bsums = (int*)alloc(1024);
    int* rowst = (int*)alloc((size_t)NN * 4);
    int* ssrc  = (int*)alloc((size_t)NE * 4);
    float* h   = (float*)alloc((size_t)NN * HH * 4);
    float* y   = (float*)alloc((size_t)NN * HH * 4);
    float* ag  = (float*)alloc((size_t)NN * HH * 4);
    unsigned short* ybf = (unsigned short*)alloc((size_t)NN * HH * 2);
    int* rank = (int*)ag;   // alias: rank only lives during CSR build, ag only during layers

    const int* esrc = ei;
    const int* edst = ei + NE;

    hipMemsetAsync(d_ws, 0, zero_end, stream);

    k_hist2<<<(NE + 255) / 256, 256, 0, stream>>>(edst, counts, rank);
    k_scan1<<<SCAN_BLOCKS, 256, 0, stream>>>(counts, rowst, bsums);
    k_scan2<<<1, 256, 0, stream>>>(bsums);
    k_scan3<<<SCAN_BLOCKS, 256, 0, stream>>>(counts, rowst, bsums);
    k_scatter2<<<(NE + 255) / 256, 256, 0, stream>>>(esrc, edst, rank, rowst, ssrc);
    k_encoder<<<(NN + 3) / 4, 256, 0, stream>>>(x, nodeW, nodeB, h, ybf);

    for (int l = 0; l < NL; ++l) {
        const float* yin = (l == 0) ? h : y;
        k_agg<<<(NN + 3) / 4, 256, 0, stream>>>(yin, ybf, rowst, counts, ssrc, tt + l, ag);
        const float* ln1g = (l < NL - 1) ? (lng + (size_t)(l + 1) * HH) : nullptr;
        const float* ln1b = (l < NL - 1) ? (lnb + (size_t)(l + 1) * HH) : nullptr;
        k_mlp<<<(NN + 63) / 64, 256, 0, stream>>>(ag,
                                                  W1 + (size_t)l * HH * H2, b1 + (size_t)l * H2,
                                                  mlg + (size_t)l * H2, mlb + (size_t)l * H2,
                                                  W2 + (size_t)l * H2 * HH, b2 + (size_t)l * HH,
                                                  (l == 0) ? (const float*)nullptr : h, h,
                                                  ln1g, ln1b, y, ybf);
    }
    k_outg<<<(NN + 63) / 64, 256, 0, stream>>>(h, lng, lnb, gW, gb, nW, nbp, out, genc);
    k_gdec<<<1, 64, 0, stream>>>(genc, out);
}

// Round 5
// 510.890 us; speedup vs baseline: 1.0858x; 1.0858x over previous
//
#include <hip/hip_runtime.h>

#define NN 50000
#define NE 800000
#define INC 32
#define HH 64
#define H2 128
#define OC 16
#define ON 17
#define NL 4
#define MEPS 1e-7f
#define LNE 1e-5f
#define SCAN_BLOCKS 196   /* ceil(50000/256) */

typedef __attribute__((ext_vector_type(8))) short bf16x8;
typedef __attribute__((ext_vector_type(4))) float f32x4;

// ---------- ordered-uint encoding for float atomic max ----------
__device__ __forceinline__ unsigned fenc(float x) {
    unsigned u = __float_as_uint(x);
    return (u & 0x80000000u) ? ~u : (u | 0x80000000u);
}
__device__ __forceinline__ float fdec(unsigned u) {
    return (u & 0x80000000u) ? __uint_as_float(u & 0x7fffffffu)
                             : __uint_as_float(~u);
}
// ---------- bf16 helpers (RNE) ----------
__device__ __forceinline__ unsigned short f2b(float x) {
    unsigned b = __float_as_uint(x);
    b += 0x7FFFu + ((b >> 16) & 1u);
    return (unsigned short)(b >> 16);
}
__device__ __forceinline__ float b2f(unsigned short u) {
    return __uint_as_float(((unsigned)u) << 16);
}

// ---------- CSR build ----------
__global__ __launch_bounds__(256) void k_hist2(const int* __restrict__ dst, int* __restrict__ counts,
                                               int* __restrict__ rank) {
    int e = blockIdx.x * 256 + threadIdx.x;
    if (e < NE) rank[e] = atomicAdd(&counts[dst[e]], 1);
}

__global__ __launch_bounds__(256) void k_scan1(const int* __restrict__ counts,
                                               int* __restrict__ incl, int* __restrict__ bsums) {
    __shared__ int s[256];
    int t = threadIdx.x;
    int i = blockIdx.x * 256 + t;
    int v = (i < NN) ? counts[i] : 0;
    s[t] = v;
    __syncthreads();
    for (int off = 1; off < 256; off <<= 1) {
        int x = (t >= off) ? s[t - off] : 0;
        __syncthreads();
        s[t] += x;
        __syncthreads();
    }
    if (i < NN) incl[i] = s[t];
    if (t == 255) bsums[blockIdx.x] = s[255];
}

__global__ __launch_bounds__(256) void k_scan2(int* __restrict__ bsums) {
    __shared__ int s[256];
    int t = threadIdx.x;
    int v = (t < SCAN_BLOCKS) ? bsums[t] : 0;
    s[t] = v;
    __syncthreads();
    for (int off = 1; off < 256; off <<= 1) {
        int x = (t >= off) ? s[t - off] : 0;
        __syncthreads();
        s[t] += x;
        __syncthreads();
    }
    if (t < SCAN_BLOCKS) bsums[t] = s[t] - v;  // exclusive
}

__global__ __launch_bounds__(256) void k_scan3(const int* __restrict__ counts,
                                               int* __restrict__ rowst, const int* __restrict__ bsums) {
    int i = blockIdx.x * 256 + threadIdx.x;
    if (i < NN) rowst[i] = rowst[i] - counts[i] + bsums[blockIdx.x];
}

__global__ __launch_bounds__(256) void k_scatter2(const int* __restrict__ src, const int* __restrict__ dst,
                                                  const int* __restrict__ rank, const int* __restrict__ rowst,
                                                  int* __restrict__ ssrc) {
    int e = blockIdx.x * 256 + threadIdx.x;
    if (e < NE) ssrc[rowst[dst[e]] + rank[e]] = src[e];
}

// ---------- weight prep: transpose + bf16 hi/lo split (one-time, trivial cost) ----------
// w1t[l][c][k] (c<128,k<64) from W1[l][k][c]; w2t[l][c][k] (c<64,k<128) from W2[l][k][c]
__global__ __launch_bounds__(256) void k_wprep(const float* __restrict__ W1, const float* __restrict__ W2,
                                               unsigned short* __restrict__ w1h, unsigned short* __restrict__ w1l,
                                               unsigned short* __restrict__ w2h, unsigned short* __restrict__ w2l) {
    int i = blockIdx.x * 256 + threadIdx.x;
    if (i >= NL * H2 * HH) return;
    int l = i / (H2 * HH), r = i % (H2 * HH);
    {
        int c = r / HH, k = r % HH;
        float v = W1[(size_t)l * HH * H2 + (size_t)k * H2 + c];
        unsigned short hi = f2b(v);
        w1h[i] = hi;
        w1l[i] = f2b(v - b2f(hi));
    }
    {
        int c = r / H2, k = r % H2;
        float v = W2[(size_t)l * H2 * HH + (size_t)k * HH + c];
        unsigned short hi = f2b(v);
        w2h[i] = hi;
        w2l[i] = f2b(v - b2f(hi));
    }
}

// ---------- node encoder: h = x @ W + b  ([N,32]@[32,64]), also bf16 shadow ----------
__global__ __launch_bounds__(256) void k_encoder(const float* __restrict__ x, const float* __restrict__ W,
                                                 const float* __restrict__ b, float* __restrict__ h,
                                                 unsigned short* __restrict__ hbf) {
    __shared__ float Ws[INC * HH];
    __shared__ float bs[HH];
    int tid = threadIdx.x;
    for (int i = tid; i < INC * HH; i += 256) Ws[i] = W[i];
    if (tid < HH) bs[tid] = b[tid];
    __syncthreads();
    int wid = tid >> 6, lane = tid & 63;
    int n = blockIdx.x * 4 + wid;
    if (n >= NN) return;
    float v = (lane < INC) ? x[(size_t)n * INC + lane] : 0.f;
    float acc = bs[lane];
    #pragma unroll
    for (int k = 0; k < INC; ++k)
        acc += __shfl(v, k) * Ws[k * HH + lane];
    h[(size_t)n * HH + lane] = acc;
    hbf[(size_t)n * HH + lane] = f2b(acc);
}

// ---------- per-dst softmax aggregation, dual-row gathers ----------
// Output: ag = agg + y in bf16 hi/lo split (feeds MFMA gemmA at ~fp32 accuracy).
__global__ __launch_bounds__(256) void k_agg(const float* __restrict__ y,
                                             const unsigned short* __restrict__ ybf,
                                             const int* __restrict__ rowst,
                                             const int* __restrict__ counts, const int* __restrict__ ssrc,
                                             const float* __restrict__ tp,
                                             unsigned short* __restrict__ agh,
                                             unsigned short* __restrict__ agl) {
    int tid = threadIdx.x;
    int wid = tid >> 6, lane = tid & 63;
    int n = blockIdx.x * 4 + wid;
    if (n >= NN) return;
    float tval = *tp;
    int start = rowst[n];
    int deg = counts[n];
    float Sa = 0.f, Sma = 0.f;
    if (deg > 0 && deg <= 64) {
        int myidx = (lane < deg) ? ssrc[start + lane] : 0;
        int half = lane >> 5;      // edge parity this lane handles
        int col = lane & 31;       // channel-pair index
        float Sa0 = 0.f, Sa1 = 0.f, Sm0 = 0.f, Sm1 = 0.f;
        for (int base = 0; base < deg; base += 16) {
            float c0[8], c1[8];
            int eidx[8];
            #pragma unroll
            for (int i = 0; i < 8; ++i) {
                int e = base + 2 * i + half;
                eidx[i] = e;
                int es = (e < deg) ? e : (deg - 1);
                int s = __shfl(myidx, es);
                unsigned v = *(const unsigned*)(ybf + (size_t)s * HH + col * 2);
                c0[i] = b2f((unsigned short)(v & 0xffffu));
                c1[i] = b2f((unsigned short)(v >> 16));
            }
            #pragma unroll
            for (int i = 0; i < 8; ++i) {
                bool ok = eidx[i] < deg;
                float m0 = fmaxf(c0[i], 0.f) + MEPS;
                float m1 = fmaxf(c1[i], 0.f) + MEPS;
                float a0 = ok ? __expf(tval * m0) : 0.f;
                float a1 = ok ? __expf(tval * m1) : 0.f;
                Sa0 += a0; Sm0 += m0 * a0;
                Sa1 += a1; Sm1 += m1 * a1;
            }
        }
        Sa0 += __shfl_xor(Sa0, 32); Sa1 += __shfl_xor(Sa1, 32);
        Sm0 += __shfl_xor(Sm0, 32); Sm1 += __shfl_xor(Sm1, 32);
        int srcl = lane >> 1;
        float saA = __shfl(Sa0, srcl), saB = __shfl(Sa1, srcl);
        float smA = __shfl(Sm0, srcl), smB = __shfl(Sm1, srcl);
        Sa = (lane & 1) ? saB : saA;
        Sma = (lane & 1) ? smB : smA;
    } else if (deg > 64) {
        for (int e = 0; e < deg; ++e) {
            int s = ssrc[start + e];
            float v = b2f(ybf[(size_t)s * HH + lane]);
            float m = fmaxf(v, 0.f) + MEPS;
            float a = __expf(tval * m);
            Sa += a; Sma += m * a;
        }
    }
    float agg = Sma / fmaxf(Sa, MEPS);  // deg==0 -> 0
    float av = agg + y[(size_t)n * HH + lane];
    unsigned short hi = f2b(av);
    agh[(size_t)n * HH + lane] = hi;
    agl[(size_t)n * HH + lane] = f2b(av - b2f(hi));
}

// ---------- MFMA fused MLP, swapped-operand form; zero block barriers ----------
// Per wave: 16 nodes. Computes U^T = mfma(W1^T, ag^T) so node = lane&15 -> LN is
// lane-local (in-lane sum + 2 shfl_xor). P round-trips through a 4.3KB/wave LDS slice
// to become gemmB's B-operand. Weights bf16 hi+lo split (~fp32 accurate); ag hi+lo too.
// D-layout (m89-verified): col=lane&15 (node), row=(lane>>4)*4+reg (weight-col).
__global__ __launch_bounds__(256) void k_mlp(
    const unsigned short* __restrict__ agh, const unsigned short* __restrict__ agl,
    const unsigned short* __restrict__ w1h, const unsigned short* __restrict__ w1l,
    const float* __restrict__ b1,
    const float* __restrict__ mlg, const float* __restrict__ mlb,
    const unsigned short* __restrict__ w2h, const unsigned short* __restrict__ w2l,
    const float* __restrict__ b2,
    const float* __restrict__ hres, float* __restrict__ hout,
    const float* __restrict__ lng1, const float* __restrict__ lnb1,
    float* __restrict__ y, unsigned short* __restrict__ ybf)
{
    __shared__ __align__(16) unsigned short Ut[4][16 * 136];  // stride 136 shorts: bank-stagger
    int tid = threadIdx.x;
    int w = tid >> 6, lane = tid & 63;
    int nl = lane & 15, g = lane >> 4;
    int node = blockIdx.x * 64 + w * 16 + nl;
    bool valid = node < NN;

    // B-frags for gemmA: ag^T tile; B[k][j]: j=lane&15=node, k=(lane>>4)*8+e
    bf16x8 bAh[2], bAl[2];
    {
        bf16x8 z = {0, 0, 0, 0, 0, 0, 0, 0};
        if (valid) {
            const unsigned short* rp = agh + (size_t)node * HH + g * 8;
            bAh[0] = *(const bf16x8*)rp;
            bAh[1] = *(const bf16x8*)(rp + 32);
            const unsigned short* rq = agl + (size_t)node * HH + g * 8;
            bAl[0] = *(const bf16x8*)rq;
            bAl[1] = *(const bf16x8*)(rq + 32);
        } else {
            bAh[0] = z; bAh[1] = z; bAl[0] = z; bAl[1] = z;
        }
    }

    // gemmA: U^T tiles (8 x 16 ucols), K=64. 3 MFMA per (t,kc): AhiBhi + AloBhi + AhiBlo
    f32x4 accU[8];
    #pragma unroll
    for (int t = 0; t < 8; ++t) {
        int uc = t * 16 + g * 4;
        float4 bb = *(const float4*)(b1 + uc);
        f32x4 a = {bb.x, bb.y, bb.z, bb.w};
        #pragma unroll
        for (int kc = 0; kc < 2; ++kc) {
            size_t wo = (size_t)(t * 16 + nl) * 64 + kc * 32 + g * 8;
            bf16x8 ah = *(const bf16x8*)(w1h + wo);
            bf16x8 al = *(const bf16x8*)(w1l + wo);
            a = __builtin_amdgcn_mfma_f32_16x16x32_bf16(ah, bAh[kc], a, 0, 0, 0);
            a = __builtin_amdgcn_mfma_f32_16x16x32_bf16(al, bAh[kc], a, 0, 0, 0);
            a = __builtin_amdgcn_mfma_f32_16x16x32_bf16(ah, bAl[kc], a, 0, 0, 0);
        }
        accU[t] = a;
    }

    // LN(128): node = lane&15 -> reduce in-lane + across the 4 lane-groups
    float s = 0.f, sq = 0.f;
    #pragma unroll
    for (int t = 0; t < 8; ++t) {
        #pragma unroll
        for (int j = 0; j < 4; ++j) { float v = accU[t][j]; s += v; sq += v * v; }
    }
    s += __shfl_xor(s, 16); sq += __shfl_xor(sq, 16);
    s += __shfl_xor(s, 32); sq += __shfl_xor(sq, 32);
    float mu = s * (1.f / 128.f);
    float var = sq * (1.f / 128.f) - mu * mu;
    float rs = rsqrtf(fmaxf(var, 0.f) + LNE);

    // normalize + relu + pack bf16 -> Ut[node][ucol]
    #pragma unroll
    for (int t = 0; t < 8; ++t) {
        int uc = t * 16 + g * 4;
        float4 gg = *(const float4*)(mlg + uc);
        float4 bb = *(const float4*)(mlb + uc);
        ushort4 pk;
        pk.x = f2b(fmaxf((accU[t][0] - mu) * rs * gg.x + bb.x, 0.f));
        pk.y = f2b(fmaxf((accU[t][1] - mu) * rs * gg.y + bb.y, 0.f));
        pk.z = f2b(fmaxf((accU[t][2] - mu) * rs * gg.z + bb.z, 0.f));
        pk.w = f2b(fmaxf((accU[t][3] - mu) * rs * gg.w + bb.w, 0.f));
        *(ushort4*)(&Ut[w][nl * 136 + uc]) = pk;
    }
    // cross-LANE (same wave) LDS dependency: drain our wave's ds_writes
    asm volatile("s_waitcnt lgkmcnt(0)" ::: "memory");

    // B-frags for gemmB: P^T; lane reads its node's 8 contiguous ucols per K-chunk
    bf16x8 bB[4];
    #pragma unroll
    for (int kc = 0; kc < 4; ++kc)
        bB[kc] = *(const bf16x8*)(&Ut[w][nl * 136 + kc * 32 + g * 8]);

    // gemmB: O^T tiles (4 x 16 ocols), K=128. 2 MFMA per (ot,kc): WhiP + WloP
    f32x4 accO[4];
    #pragma unroll
    for (int ot = 0; ot < 4; ++ot) {
        int oc = ot * 16 + g * 4;
        float4 bb = *(const float4*)(b2 + oc);
        f32x4 a = {bb.x, bb.y, bb.z, bb.w};
        #pragma unroll
        for (int kc = 0; kc < 4; ++kc) {
            size_t wo = (size_t)(ot * 16 + nl) * 128 + kc * 32 + g * 8;
            bf16x8 ah = *(const bf16x8*)(w2h + wo);
            bf16x8 al = *(const bf16x8*)(w2l + wo);
            a = __builtin_amdgcn_mfma_f32_16x16x32_bf16(ah, bB[kc], a, 0, 0, 0);
            a = __builtin_amdgcn_mfma_f32_16x16x32_bf16(al, bB[kc], a, 0, 0, 0);
        }
        accO[ot] = a;
    }

    // epilogue: +residual, write h
    float4 oo[4];
    #pragma unroll
    for (int ot = 0; ot < 4; ++ot) {
        int oc = ot * 16 + g * 4;
        float4 o;
        o.x = accO[ot][0]; o.y = accO[ot][1]; o.z = accO[ot][2]; o.w = accO[ot][3];
        if (valid) {
            if (hres) {
                float4 hr = *(const float4*)(hres + (size_t)node * HH + oc);
                o.x += hr.x; o.y += hr.y; o.z += hr.z; o.w += hr.w;
            }
            *(float4*)(hout + (size_t)node * HH + oc) = o;
        }
        oo[ot] = o;
    }
    if (!lng1) return;   // last layer: k_outg does the final LN (uniform exit)

    // next-layer LN(64)+ReLU, all in registers
    float s2 = 0.f, sq2 = 0.f;
    #pragma unroll
    for (int ot = 0; ot < 4; ++ot) {
        s2 += oo[ot].x + oo[ot].y + oo[ot].z + oo[ot].w;
        sq2 += oo[ot].x * oo[ot].x + oo[ot].y * oo[ot].y
             + oo[ot].z * oo[ot].z + oo[ot].w * oo[ot].w;
    }
    s2 += __shfl_xor(s2, 16); sq2 += __shfl_xor(sq2, 16);
    s2 += __shfl_xor(s2, 32); sq2 += __shfl_xor(sq2, 32);
    float mu2 = s2 * (1.f / 64.f);
    float var2 = sq2 * (1.f / 64.f) - mu2 * mu2;
    float rs2 = rsqrtf(fmaxf(var2, 0.f) + LNE);
    #pragma unroll
    for (int ot = 0; ot < 4; ++ot) {
        int oc = ot * 16 + g * 4;
        float4 gg = *(const float4*)(lng1 + oc);
        float4 bb = *(const float4*)(lnb1 + oc);
        float4 v;
        v.x = fmaxf((oo[ot].x - mu2) * rs2 * gg.x + bb.x, 0.f);
        v.y = fmaxf((oo[ot].y - mu2) * rs2 * gg.y + bb.y, 0.f);
        v.z = fmaxf((oo[ot].z - mu2) * rs2 * gg.z + bb.z, 0.f);
        v.w = fmaxf((oo[ot].w - mu2) * rs2 * gg.w + bb.w, 0.f);
        if (valid) {
            *(float4*)(y + (size_t)node * HH + oc) = v;
            ushort4 p;
            p.x = f2b(v.x); p.y = f2b(v.y); p.z = f2b(v.z); p.w = f2b(v.w);
            *(ushort4*)(ybf + (size_t)node * HH + oc) = p;
        }
    }
}

// ---------- fused final LN + both heads (no fence; k_gdec decodes) ----------
__global__ __launch_bounds__(256) void k_outg(const float* __restrict__ h,
                                              const float* __restrict__ lng, const float* __restrict__ lnb,
                                              const float* __restrict__ gW, const float* __restrict__ gb,
                                              const float* __restrict__ nW, const float* __restrict__ nbp,
                                              float* __restrict__ dout, unsigned* __restrict__ genc) {
    __shared__ float As[64 * 68];     // h tile, then normalized in place
    __shared__ float WcT[33 * 68];    // [j][k]: j<17 n-head, j in [17,33) g-head
    __shared__ float Os[64 * 40];     // output tile
    __shared__ float bs[40];
    __shared__ float lg[HH], lb[HH];
    __shared__ float ps[256], psq[256];
    __shared__ float mus[64], rss[64];
    int tid = threadIdx.x;
    int nb = blockIdx.x * 64;
    for (int i = tid; i < HH * ON; i += 256) { int k = i / ON, j = i - k * ON; WcT[j * 68 + k] = nW[i]; }
    for (int i = tid; i < HH * OC; i += 256) { int k = i / OC, j = i - k * OC; WcT[(ON + j) * 68 + k] = gW[i]; }
    if (tid < ON) bs[tid] = nbp[tid];
    else if (tid < 33) bs[tid] = gb[tid - ON];
    if (tid < HH) { lg[tid] = lng[tid]; lb[tid] = lnb[tid]; }
    {
        int row = tid >> 2, cb = (tid & 3) * 16;
        int n = nb + row;
        float4* dp = (float4*)(As + row * 68 + cb);
        if (n < NN) {
            const float4* sp = (const float4*)(h + (size_t)n * HH + cb);
            #pragma unroll
            for (int i = 0; i < 4; ++i) dp[i] = sp[i];
        } else {
            float4 z = {0.f, 0.f, 0.f, 0.f};
            #pragma unroll
            for (int i = 0; i < 4; ++i) dp[i] = z;
        }
    }
    __syncthreads();
    {
        int row = tid >> 2, q = tid & 3;
        const float* rp = As + row * 68;
        float s = 0.f, sq = 0.f;
        #pragma unroll
        for (int i = 0; i < 16; ++i) { float v = rp[q + 4 * i]; s += v; sq += v * v; }
        ps[tid] = s; psq[tid] = sq;
    }
    __syncthreads();
    if (tid < 64) {
        float s = ps[tid * 4] + ps[tid * 4 + 1] + ps[tid * 4 + 2] + ps[tid * 4 + 3];
        float sq = psq[tid * 4] + psq[tid * 4 + 1] + psq[tid * 4 + 2] + psq[tid * 4 + 3];
        float mu = s * (1.f / 64.f);
        float var = sq * (1.f / 64.f) - mu * mu;
        mus[tid] = mu;
        rss[tid] = rsqrtf(fmaxf(var, 0.f) + LNE);
    }
    __syncthreads();
    {
        int row = tid >> 2, q = tid & 3;
        float mu = mus[row], rs = rss[row];
        float* rp = As + row * 68;
        #pragma unroll
        for (int i = 0; i < 16; ++i) {
            int c = q + 4 * i;
            rp[c] = fmaxf((rp[c] - mu) * rs * lg[c] + lb[c], 0.f);
        }
    }
    __syncthreads();
    int tx = tid & 15, ty = tid >> 4;
    int r0 = ty * 4;
    float acc[4][3];
    #pragma unroll
    for (int r = 0; r < 4; ++r) {
        acc[r][0] = bs[tx]; acc[r][1] = bs[tx + 16]; acc[r][2] = bs[32];
    }
    #pragma unroll
    for (int k = 0; k < HH; k += 4) {
        float4 w0 = *(const float4*)(WcT + tx * 68 + k);
        float4 w1 = *(const float4*)(WcT + (16 + tx) * 68 + k);
        float4 w2 = *(const float4*)(WcT + 32 * 68 + k);
        #pragma unroll
        for (int r = 0; r < 4; ++r) {
            float4 a = *(const float4*)(As + (r0 + r) * 68 + k);
            acc[r][0] += a.x * w0.x + a.y * w0.y + a.z * w0.z + a.w * w0.w;
            acc[r][1] += a.x * w1.x + a.y * w1.y + a.z * w1.z + a.w * w1.w;
            acc[r][2] += a.x * w2.x + a.y * w2.y + a.z * w2.z + a.w * w2.w;
        }
    }
    #pragma unroll
    for (int r = 0; r < 4; ++r) {
        Os[(r0 + r) * 40 + tx] = acc[r][0];
        Os[(r0 + r) * 40 + 16 + tx] = acc[r][1];
        if (tx == 0) Os[(r0 + r) * 40 + 32] = acc[r][2];
    }
    __syncthreads();
    // n-head store: linear index is exactly row-major [n][17] -> coalesced
    for (int i = tid; i < 64 * ON; i += 256) {
        int r = i / ON, j = i - r * ON;
        int n = nb + r;
        if (n < NN) dout[OC + (size_t)n * ON + j] = Os[r * 40 + j];
    }
    // g-head block max
    if (tid < OC) {
        int rmax = NN - nb; if (rmax > 64) rmax = 64;
        float m = -INFINITY;
        for (int r = 0; r < rmax; ++r) m = fmaxf(m, Os[r * 40 + ON + tid]);
        atomicMax(&genc[tid], fenc(m));
    }
}

__global__ void k_gdec(const unsigned* __restrict__ genc, float* __restrict__ dout) {
    int t = threadIdx.x;
    if (t < OC) dout[t] = fdec(genc[t]);
}

// ---------- launch ----------
extern "C" void kernel_launch(void* const* d_in, const int* in_sizes, int n_in,
                              void* d_out, int out_size, void* d_ws, size_t ws_size,
                              hipStream_t stream) {
    const float* x     = (const float*)d_in[0];
    const float* nodeW = (const float*)d_in[1];
    const float* nodeB = (const float*)d_in[2];
    const float* W1    = (const float*)d_in[3];
    const float* b1    = (const float*)d_in[4];
    const float* mlg   = (const float*)d_in[5];
    const float* mlb   = (const float*)d_in[6];
    const float* W2    = (const float*)d_in[7];
    const float* b2    = (const float*)d_in[8];
    const float* tt    = (const float*)d_in[9];
    const float* lng   = (const float*)d_in[10];
    const float* lnb   = (const float*)d_in[11];
    const int*   ei    = (const int*)d_in[12];
    const float* gW    = (const float*)d_in[13];
    const float* gb    = (const float*)d_in[14];
    const float* nW    = (const float*)d_in[15];
    const float* nbp   = (const float*)d_in[16];
    float* out = (float*)d_out;

    char* ws = (char*)d_ws;
    size_t off = 0;
    auto alloc = [&](size_t bytes) -> void* {
        void* p = ws + off;
        off = (off + bytes + 255) & ~(size_t)255;
        return p;
    };
    int* counts    = (int*)alloc((size_t)NN * 4);
    unsigned* genc = (unsigned*)alloc(64);
    size_t zero_end = off;
    int* bsums = (int*)alloc(1024);
    int* rowst = (int*)alloc((size_t)NN * 4);
    int* ssrc  = (int*)alloc((size_t)NE * 4);
    float* h   = (float*)alloc((size_t)NN * HH * 4);
    float* y   = (float*)alloc((size_t)NN * HH * 4);
    unsigned short* agh = (unsigned short*)alloc((size_t)NN * HH * 2);
    unsigned short* agl = (unsigned short*)alloc((size_t)NN * HH * 2);
    unsigned short* ybf = (unsigned short*)alloc((size_t)NN * HH * 2);
    unsigned short* w1h = (unsigned short*)alloc((size_t)NL * H2 * HH * 2);
    unsigned short* w1l = (unsigned short*)alloc((size_t)NL * H2 * HH * 2);
    unsigned short* w2h = (unsigned short*)alloc((size_t)NL * H2 * HH * 2);
    unsigned short* w2l = (unsigned short*)alloc((size_t)NL * H2 * HH * 2);
    int* rank = (int*)agh;   // alias: rank only lives during CSR build (3.2MB <= 6.4MB)

    const int* esrc = ei;
    const int* edst = ei + NE;

    hipMemsetAsync(d_ws, 0, zero_end, stream);

    k_wprep<<<(NL * H2 * HH + 255) / 256, 256, 0, stream>>>(W1, W2, w1h, w1l, w2h, w2l);
    k_hist2<<<(NE + 255) / 256, 256, 0, stream>>>(edst, counts, rank);
    k_scan1<<<SCAN_BLOCKS, 256, 0, stream>>>(counts, rowst, bsums);
    k_scan2<<<1, 256, 0, stream>>>(bsums);
    k_scan3<<<SCAN_BLOCKS, 256, 0, stream>>>(counts, rowst, bsums);
    k_scatter2<<<(NE + 255) / 256, 256, 0, stream>>>(esrc, edst, rank, rowst, ssrc);
    k_encoder<<<(NN + 3) / 4, 256, 0, stream>>>(x, nodeW, nodeB, h, ybf);

    for (int l = 0; l < NL; ++l) {
        const float* yin = (l == 0) ? h : y;
        k_agg<<<(NN + 3) / 4, 256, 0, stream>>>(yin, ybf, rowst, counts, ssrc, tt + l, agh, agl);
        const float* ln1g = (l < NL - 1) ? (lng + (size_t)(l + 1) * HH) : nullptr;
        const float* ln1b = (l < NL - 1) ? (lnb + (size_t)(l + 1) * HH) : nullptr;
        k_mlp<<<(NN + 63) / 64, 256, 0, stream>>>(agh, agl,
                                                  w1h + (size_t)l * H2 * HH, w1l + (size_t)l * H2 * HH,
                                                  b1 + (size_t)l * H2,
                                                  mlg + (size_t)l * H2, mlb + (size_t)l * H2,
                                                  w2h + (size_t)l * H2 * HH, w2l + (size_t)l * H2 * HH,
                                                  b2 + (size_t)l * HH,
                                                  (l == 0) ? (const float*)nullptr : h, h,
                                                  ln1g, ln1b, y, ybf);
    }
    k_outg<<<(NN + 63) / 64, 256, 0, stream>>>(h, lng, lnb, gW, gb, nW, nbp, out, genc);
    k_gdec<<<1, 64, 0, stream>>>(genc, out);
}